// Round 6
// baseline (10190.822 us; speedup 1.0000x reference)
//
#include <hip/hip_runtime.h>

// SimpleRNN: B=64,T=512,I=128,H=1024,L=4,O=128
// Round 6: round-5 fused design with the chunk-counter deadlock fixed:
// layers 1..3 have 32 xin tile-units per chunk (not 64). Rec chunk-entry
// wait target is now l==0 ? 64 : 32, and seq-ring back-pressure target 32.
// 64 rec blocks (128 neurons, Whh-only in regs, 8-member sync domains) +
// 192 GEMM blocks (xin = seq@Wih^T, layer-0 input proj, FC) in 16-step
// chunks off the critical path. All cross-block data relaxed agent(sc1)
// atomics; monotonic-counter waits (r4-proven ballot-poll).
#define B_ 64
#define T_ 512
#define I_ 128
#define H_ 1024
#define L_ 4
#define O_ 128
#define M_ (B_ * T_)
#define S_ 16               // chunk steps
#define NCH 32              // T_/S_
#define ROWS 1024           // S_*B_ rows per chunk
#define UPC 168             // units/chunk: l0 64, l1..3 32 each, FC 8
#define NU (NCH * UPC)      // 5376
#define NGEMM 192

typedef __attribute__((ext_vector_type(8))) short bf16x8_t;
typedef __attribute__((ext_vector_type(4))) float f32x4_t;

__device__ __forceinline__ unsigned short f2bf(float v) {
  unsigned int u = __builtin_bit_cast(unsigned int, v);
  u += 0x7FFFu + ((u >> 16) & 1u);
  return (unsigned short)(u >> 16);
}
__device__ __forceinline__ float bf2f(unsigned short h) {
  return __builtin_bit_cast(float, ((unsigned int)h) << 16);
}
__device__ __forceinline__ f32x4_t mfma16(bf16x8_t a, bf16x8_t b, f32x4_t c) {
  return __builtin_amdgcn_mfma_f32_16x16x32_bf16(a, b, c, 0, 0, 0);
}
__device__ __forceinline__ unsigned aldc(const unsigned* p) {
  return __hip_atomic_load(p, __ATOMIC_RELAXED, __HIP_MEMORY_SCOPE_AGENT);
}
__device__ __forceinline__ unsigned long long ald64(const unsigned long long* p) {
  return __hip_atomic_load(p, __ATOMIC_RELAXED, __HIP_MEMORY_SCOPE_AGENT);
}
__device__ __forceinline__ void ast32(unsigned* p, unsigned v) {
  __hip_atomic_store(p, v, __ATOMIC_RELAXED, __HIP_MEMORY_SCOPE_AGENT);
}

// Poll 16 counter lines (stride 32 u32) until all >= target; return group min.
__device__ __forceinline__ unsigned wait16min(const unsigned* base, unsigned target) {
  const int i = threadIdx.x & 15;
  unsigned v;
  while (true) {
    v = aldc(base + i * 32);
    if (__ballot(v < target) == 0ull) break;
    __builtin_amdgcn_s_sleep(4);
  }
  unsigned mn = v;
  mn = min(mn, (unsigned)__shfl_xor((int)mn, 1));
  mn = min(mn, (unsigned)__shfl_xor((int)mn, 2));
  mn = min(mn, (unsigned)__shfl_xor((int)mn, 4));
  mn = min(mn, (unsigned)__shfl_xor((int)mn, 8));
  return mn;
}
// Single-counter wait; one wave spins, the rest park on the barrier.
__device__ __forceinline__ void wait_cnt_blk(const unsigned* p, unsigned target) {
  if (threadIdx.x < 64) {
    while (aldc(p) < target) __builtin_amdgcn_s_sleep(8);
  }
  __syncthreads();
}

// ---------------------------------------------------------------------------
// GEMM tiles (derived from round-1 proven gemm_k).
// ---------------------------------------------------------------------------
// xin tile for layers 1..3: 128 rows x 256 cols, K=1024, B hi-only (1 MFMA).
__device__ void tile_seq(const unsigned short* __restrict__ A,
                         const float* __restrict__ W,
                         const float* __restrict__ b1, const float* __restrict__ b2,
                         unsigned* __restrict__ xo, int mt, int ng,
                         unsigned short* smem) {
  const int tid = threadIdx.x;
  const int wave = tid >> 6, lane = tid & 63;
  const int wm = wave >> 1, wn = wave & 1;
  const int lm = lane & 15, lk = lane >> 4;
  unsigned short* Ah = smem;          // 8192 u16
  unsigned short* Bh = smem + 8192;   // 16384 u16
  f32x4_t acc[4][8] = {};
  for (int kc = 0; kc < H_; kc += 64) {
    __syncthreads();
#pragma unroll
    for (int p = 0; p < 4; ++p) {
      int fl = p * 256 + tid;
      int row = fl & 127, ks = fl >> 7;
      int kk = kc + (ks >> 2) * 32 + (ks & 3) * 8;
      const unsigned long long* s8 =
          (const unsigned long long*)(A + (size_t)(mt * 128 + row) * H_ + kk);
      unsigned long long w0 = ald64(s8), w1 = ald64(s8 + 1);
      *(unsigned long long*)(Ah + fl * 8) = w0;
      *(unsigned long long*)(Ah + fl * 8 + 4) = w1;
    }
#pragma unroll
    for (int p = 0; p < 8; ++p) {
      int fl = p * 256 + tid;
      int col = fl & 255, ks = fl >> 8;
      int kk = kc + (ks >> 2) * 32 + (ks & 3) * 8;
      const float* src = W + (size_t)(ng * 256 + col) * H_ + kk;
      union { bf16x8_t s; unsigned short u[8]; } th;
#pragma unroll
      for (int e = 0; e < 8; ++e) th.u[e] = (short)f2bf(src[e]);
      *(bf16x8_t*)(Bh + fl * 8) = th.s;
    }
    __syncthreads();
#pragma unroll
    for (int kit = 0; kit < 2; ++kit) {
      bf16x8_t bfr[8];
#pragma unroll
      for (int n = 0; n < 8; ++n)
        bfr[n] = *(const bf16x8_t*)(Bh + ((kit * 4 + lk) * 256 + wn * 128 + n * 16 + lm) * 8);
#pragma unroll
      for (int m = 0; m < 4; ++m) {
        bf16x8_t a = *(const bf16x8_t*)(Ah + ((kit * 4 + lk) * 128 + wm * 64 + m * 16 + lm) * 8);
#pragma unroll
        for (int n = 0; n < 8; ++n) acc[m][n] = mfma16(a, bfr[n], acc[m][n]);
      }
    }
  }
#pragma unroll
  for (int n = 0; n < 8; ++n) {
    int col = ng * 256 + wn * 128 + n * 16 + lm;
    float bv = b1[col] + b2[col];
#pragma unroll
    for (int m = 0; m < 4; ++m) {
#pragma unroll
      for (int r = 0; r < 4; ++r) {
        int row = mt * 128 + wm * 64 + m * 16 + lk * 4 + r;
        unsigned hv = f2bf(acc[m][n][r] + bv);
        unsigned ov = (unsigned)__shfl_xor((int)hv, 1);
        if (!(lm & 1)) ast32(xo + (size_t)row * (H_ / 2) + (col >> 1), hv | (ov << 16));
      }
    }
  }
}

// layer-0 input projection: A = x fp32 (split hi/lo), B = Wih0 hi/lo, K=128,
// 128x128 tile, 3-term MFMA (round-1 ASPLIT math).
__device__ void tile_l0(const float* __restrict__ x, int c,
                        const float* __restrict__ W,
                        const float* __restrict__ b1, const float* __restrict__ b2,
                        unsigned* __restrict__ xo, int mt, int nt,
                        unsigned short* smem) {
  const int tid = threadIdx.x;
  const int wave = tid >> 6, lane = tid & 63;
  const int wm = wave >> 1, wn = wave & 1;
  const int lm = lane & 15, lk = lane >> 4;
  unsigned short* Ahi = smem;
  unsigned short* Alo = smem + 8192;
  unsigned short* Bhi = smem + 16384;
  unsigned short* Blo = smem + 24576;
  f32x4_t acc[4][4] = {};
  for (int kc = 0; kc < I_; kc += 64) {
    __syncthreads();
#pragma unroll
    for (int p = 0; p < 4; ++p) {
      int fl = p * 256 + tid;
      int row = fl & 127, ks = fl >> 7;
      int kk = kc + (ks >> 2) * 32 + (ks & 3) * 8;
      int srow = mt * 128 + row;
      int b = srow & 63, tl = srow >> 6;
      const float* src = x + ((size_t)b * T_ + c * S_ + tl) * I_ + kk;
      union { bf16x8_t s; unsigned short u[8]; } th, tl2;
#pragma unroll
      for (int e = 0; e < 8; ++e) {
        float v = src[e];
        unsigned short h = f2bf(v);
        th.u[e] = (short)h;
        tl2.u[e] = (short)f2bf(v - bf2f(h));
      }
      *(bf16x8_t*)(Ahi + fl * 8) = th.s;
      *(bf16x8_t*)(Alo + fl * 8) = tl2.s;
    }
#pragma unroll
    for (int p = 0; p < 4; ++p) {
      int fl = p * 256 + tid;
      int row = fl & 127, ks = fl >> 7;
      int kk = kc + (ks >> 2) * 32 + (ks & 3) * 8;
      const float* src = W + (size_t)(nt * 128 + row) * I_ + kk;
      union { bf16x8_t s; unsigned short u[8]; } th, tl2;
#pragma unroll
      for (int e = 0; e < 8; ++e) {
        float v = src[e];
        unsigned short h = f2bf(v);
        th.u[e] = (short)h;
        tl2.u[e] = (short)f2bf(v - bf2f(h));
      }
      *(bf16x8_t*)(Bhi + fl * 8) = th.s;
      *(bf16x8_t*)(Blo + fl * 8) = tl2.s;
    }
    __syncthreads();
#pragma unroll
    for (int kit = 0; kit < 2; ++kit) {
      bf16x8_t bhf[4], blf[4];
#pragma unroll
      for (int n = 0; n < 4; ++n) {
        int off = ((kit * 4 + lk) * 128 + wn * 64 + n * 16 + lm) * 8;
        bhf[n] = *(const bf16x8_t*)(Bhi + off);
        blf[n] = *(const bf16x8_t*)(Blo + off);
      }
#pragma unroll
      for (int m = 0; m < 4; ++m) {
        int off = ((kit * 4 + lk) * 128 + wm * 64 + m * 16 + lm) * 8;
        bf16x8_t a = *(const bf16x8_t*)(Ahi + off);
        bf16x8_t al = *(const bf16x8_t*)(Alo + off);
#pragma unroll
        for (int n = 0; n < 4; ++n) {
          acc[m][n] = mfma16(a, bhf[n], acc[m][n]);
          acc[m][n] = mfma16(a, blf[n], acc[m][n]);
          acc[m][n] = mfma16(al, bhf[n], acc[m][n]);
        }
      }
    }
  }
#pragma unroll
  for (int n = 0; n < 4; ++n) {
    int col = nt * 128 + wn * 64 + n * 16 + lm;
    float bv = b1[col] + b2[col];
#pragma unroll
    for (int m = 0; m < 4; ++m) {
#pragma unroll
      for (int r = 0; r < 4; ++r) {
        int row = mt * 128 + wm * 64 + m * 16 + lk * 4 + r;
        unsigned hv = f2bf(acc[m][n][r] + bv);
        unsigned ov = (unsigned)__shfl_xor((int)hv, 1);
        if (!(lm & 1)) ast32(xo + (size_t)row * (H_ / 2) + (col >> 1), hv | (ov << 16));
      }
    }
  }
}

// FC tile: A = seqr l3 chunk (u16 sc1), B = Wfc hi/lo, N=128, out fp32.
__device__ void tile_fc(const unsigned short* __restrict__ A,
                        const float* __restrict__ W, const float* __restrict__ bfc,
                        float* __restrict__ out, int c, int mt,
                        unsigned short* smem) {
  const int tid = threadIdx.x;
  const int wave = tid >> 6, lane = tid & 63;
  const int wm = wave >> 1, wn = wave & 1;
  const int lm = lane & 15, lk = lane >> 4;
  unsigned short* Ah = smem;
  unsigned short* Bhi = smem + 8192;
  unsigned short* Blo = smem + 16384;
  f32x4_t acc[4][4] = {};
  for (int kc = 0; kc < H_; kc += 64) {
    __syncthreads();
#pragma unroll
    for (int p = 0; p < 4; ++p) {
      int fl = p * 256 + tid;
      int row = fl & 127, ks = fl >> 7;
      int kk = kc + (ks >> 2) * 32 + (ks & 3) * 8;
      const unsigned long long* s8 =
          (const unsigned long long*)(A + (size_t)(mt * 128 + row) * H_ + kk);
      unsigned long long w0 = ald64(s8), w1 = ald64(s8 + 1);
      *(unsigned long long*)(Ah + fl * 8) = w0;
      *(unsigned long long*)(Ah + fl * 8 + 4) = w1;
    }
#pragma unroll
    for (int p = 0; p < 4; ++p) {
      int fl = p * 256 + tid;
      int col = fl & 127, ks = fl >> 7;
      int kk = kc + (ks >> 2) * 32 + (ks & 3) * 8;
      const float* src = W + (size_t)col * H_ + kk;
      union { bf16x8_t s; unsigned short u[8]; } th, tl2;
#pragma unroll
      for (int e = 0; e < 8; ++e) {
        float v = src[e];
        unsigned short h = f2bf(v);
        th.u[e] = (short)h;
        tl2.u[e] = (short)f2bf(v - bf2f(h));
      }
      *(bf16x8_t*)(Bhi + fl * 8) = th.s;
      *(bf16x8_t*)(Blo + fl * 8) = tl2.s;
    }
    __syncthreads();
#pragma unroll
    for (int kit = 0; kit < 2; ++kit) {
      bf16x8_t bhf[4], blf[4];
#pragma unroll
      for (int n = 0; n < 4; ++n) {
        int off = ((kit * 4 + lk) * 128 + wn * 64 + n * 16 + lm) * 8;
        bhf[n] = *(const bf16x8_t*)(Bhi + off);
        blf[n] = *(const bf16x8_t*)(Blo + off);
      }
#pragma unroll
      for (int m = 0; m < 4; ++m) {
        bf16x8_t a = *(const bf16x8_t*)(Ah + ((kit * 4 + lk) * 128 + wm * 64 + m * 16 + lm) * 8);
#pragma unroll
        for (int n = 0; n < 4; ++n) {
          acc[m][n] = mfma16(a, bhf[n], acc[m][n]);
          acc[m][n] = mfma16(a, blf[n], acc[m][n]);
        }
      }
    }
  }
#pragma unroll
  for (int n = 0; n < 4; ++n) {
    int col = wn * 64 + n * 16 + lm;
    float bv = bfc[col];
#pragma unroll
    for (int m = 0; m < 4; ++m) {
#pragma unroll
      for (int r = 0; r < 4; ++r) {
        int srow = mt * 128 + wm * 64 + m * 16 + lk * 4 + r;
        int b = srow & 63, tl = srow >> 6;
        out[((size_t)b * T_ + c * S_ + tl) * O_ + col] = acc[m][n][r] + bv;
      }
    }
  }
}

// ---------------------------------------------------------------------------
// Fused persistent kernel.
// bid < 64: recurrence block. l=bid>>4, bg=(bid>>3)&1 (32 batches), me=bid&7
//   (128 neurons). Whh B-frags (bf16-hi) in ~256 VGPRs. Per step: 8-member
//   ballot barrier, 64KB h-slice sc1 load -> LDS, 128 MFMA/wave, epilogue.
// bid >= 64: GEMM block. Static work list over (chunk, kind, tile) with
//   monotonic-counter deps. Units/chunk: l0=64, l1..3=32 each, FC=8.
// ---------------------------------------------------------------------------
__global__ __launch_bounds__(256, 1) void fused_k(
    const float* __restrict__ x, const float* __restrict__ hidden,
    const float* __restrict__ Wih0, const float* __restrict__ Whh0,
    const float* __restrict__ bih0, const float* __restrict__ bhh0,
    const float* __restrict__ WihL, const float* __restrict__ WhhL,
    const float* __restrict__ bihL, const float* __restrict__ bhhL,
    const float* __restrict__ Wfc, const float* __restrict__ bfc,
    float* __restrict__ out, float* __restrict__ hn,
    unsigned* __restrict__ rprog, unsigned* __restrict__ gchunk,
    unsigned* __restrict__ gfc,
    unsigned short* __restrict__ ring, unsigned short* __restrict__ xin,
    unsigned short* __restrict__ seqr) {
  extern __shared__ char lds[];
  const int tid = threadIdx.x;
  const int wave = tid >> 6, lane = tid & 63;
  const int lm = lane & 15, lk = lane >> 4;
  const int bid = blockIdx.x;

  if (bid < 64) {
    // ===================== recurrence role =====================
    const int l = bid >> 4, sub = bid & 15, bg = sub >> 3, me = sub & 7;
    const int j0 = me * 128 + wave * 32;

    const float* Whh = (l == 0) ? Whh0 : WhhL + (size_t)(l - 1) * H_ * H_;
    bf16x8_t bh0[32], bh1[32];
#pragma unroll
    for (int kit = 0; kit < 32; ++kit) {
      const float* s0 = Whh + (size_t)(j0 + lm) * H_ + kit * 32 + lk * 8;
      const float* s1 = Whh + (size_t)(j0 + 16 + lm) * H_ + kit * 32 + lk * 8;
      union { bf16x8_t s; unsigned short u[8]; } t0, t1;
#pragma unroll
      for (int e = 0; e < 8; ++e) {
        t0.u[e] = (short)f2bf(s0[e]);
        t1.u[e] = (short)f2bf(s1[e]);
      }
      bh0[kit] = t0.s;
      bh1[kit] = t1.s;
    }

    // init h0 -> ring slot 1 (this block's 128-neuron x 32-batch portion)
    {
      unsigned* r1 = (unsigned*)(ring + ((size_t)(l * 2 + bg) * 2 + 1) * 32768);
#pragma unroll
      for (int q = 0; q < 8; ++q) {
        int g32 = me * 2048 + q * 256 + tid;
        int joct = g32 >> 7, rem = g32 & 127;
        int b32 = rem >> 2, jp = rem & 3;
        int je = joct * 8 + jp * 2;
        const float* hp = hidden + (size_t)l * B_ * H_ + (bg * 32 + b32) * H_ + je;
        ast32(r1 + g32, (unsigned)f2bf(hp[0]) | ((unsigned)f2bf(hp[1]) << 16));
      }
    }
    __syncthreads();  // drains vmcnt -> release
    unsigned* myline = rprog + ((size_t)((l * 2 + bg) * 8 + me)) * 32;
    if (tid == 0) ast32(myline, 1u);
    const unsigned* ownB = rprog + (size_t)(l * 2 + bg) * 8 * 32;

    for (int t = 0; t < T_; ++t) {
      const int c = t >> 4;
      if ((t & 15) == 0) {
        // xin chunk ready for this layer (l0: 64 tiles, l1..3: 32 tiles)
        wait_cnt_blk(gchunk + (size_t)(l * NCH + c) * 32, l == 0 ? 64u : 32u);
        // seq ring back-pressure (depth 4); consumers: l+1 xin (32) or FC (8)
        if (c >= 4) {
          if (l < 3) wait_cnt_blk(gchunk + (size_t)((l + 1) * NCH + (c - 4)) * 32, 32u);
          else       wait_cnt_blk(gfc + (size_t)(c - 4) * 32, 8u);
        }
      }
      // xin loads (independent of h barrier)
      const unsigned* xb = (const unsigned*)xin + (size_t)(l * 2 + (c & 1)) * (ROWS * H_ / 2);
      unsigned xv[2][2][4];
#pragma unroll
      for (int nt = 0; nt < 2; ++nt)
#pragma unroll
        for (int bt = 0; bt < 2; ++bt)
#pragma unroll
          for (int r = 0; r < 4; ++r) {
            int b = bg * 32 + bt * 16 + lk * 4 + r;
            int row = (t & 15) * 64 + b;
            int j = j0 + nt * 16 + lm;
            xv[nt][bt][r] = aldc(xb + (size_t)row * (H_ / 2) + (j >> 1));
          }
      // own-group barrier: all 8 members finished step t-1
      {
        const int i = tid & 7;
        while (true) {
          unsigned v = aldc(ownB + i * 32);
          if (__ballot(v < (unsigned)(t + 1)) == 0ull) break;
          __builtin_amdgcn_s_sleep(1);
        }
      }
      // h slice (64 KB) -> LDS
      {
        const unsigned long long* hp64 = (const unsigned long long*)(
            ring + ((size_t)(l * 2 + bg) * 2 + ((t & 1) ^ 1)) * 32768);
        unsigned long long ht[32];
#pragma unroll
        for (int i = 0; i < 32; ++i) ht[i] = ald64(hp64 + i * 256 + tid);
#pragma unroll
        for (int i = 0; i < 32; ++i)
          ((unsigned long long*)lds)[i * 256 + tid] = ht[i];
      }
      __syncthreads();
      // MFMA: acc over 32 k-iterations; A-frags shared across the two n-tiles
      f32x4_t acc00 = {0.f, 0.f, 0.f, 0.f}, acc01 = acc00, acc10 = acc00, acc11 = acc00;
#pragma unroll
      for (int kit = 0; kit < 32; ++kit) {
        const char* fo = lds + (size_t)((kit * 4 + lk) * 32) * 16;
        bf16x8_t a0 = *(const bf16x8_t*)(fo + (size_t)lm * 16);
        bf16x8_t a1 = *(const bf16x8_t*)(fo + (size_t)(16 + lm) * 16);
        acc00 = mfma16(a0, bh0[kit], acc00);
        acc01 = mfma16(a1, bh0[kit], acc01);
        acc10 = mfma16(a0, bh1[kit], acc10);
        acc11 = mfma16(a1, bh1[kit], acc11);
      }
      // epilogue
      unsigned* rw = (unsigned*)(ring + ((size_t)(l * 2 + bg) * 2 + (t & 1)) * 32768);
      unsigned* sw = (unsigned*)(seqr + (size_t)(l * 4 + (c & 3)) * (ROWS * H_));
      const bool evenl = !(lm & 1);
#pragma unroll
      for (int bt = 0; bt < 2; ++bt) {
#pragma unroll
        for (int r = 0; r < 4; ++r) {
          const int b32 = bt * 16 + lk * 4 + r;
          const int b = bg * 32 + b32;
          const int row = (t & 15) * 64 + b;
          const f32x4_t* p0 = bt ? &acc01 : &acc00;
          const f32x4_t* p1 = bt ? &acc11 : &acc10;
          float v0 = (*p0)[r] + bf2f((unsigned short)(xv[0][bt][r] >> ((lm & 1) * 16)));
          float v1 = (*p1)[r] + bf2f((unsigned short)(xv[1][bt][r] >> ((lm & 1) * 16)));
          v0 = fmaxf(v0, 0.f);
          v1 = fmaxf(v1, 0.f);
          unsigned h0v = f2bf(v0), h1v = f2bf(v1);
          unsigned o0 = (unsigned)__shfl_xor((int)h0v, 1);
          unsigned o1 = (unsigned)__shfl_xor((int)h1v, 1);
          if (evenl) {
            int j = j0 + lm;  // even
            unsigned pk = h0v | (o0 << 16);
            ast32(rw + ((j >> 3) * 32 + b32) * 4 + ((j & 7) >> 1), pk);
            ast32(sw + (size_t)row * (H_ / 2) + (j >> 1), pk);
          } else {
            int j = j0 + 16 + lm;  // odd
            int ja = j & ~1;
            unsigned pk = o1 | (h1v << 16);
            ast32(rw + ((ja >> 3) * 32 + b32) * 4 + ((ja & 7) >> 1), pk);
            ast32(sw + (size_t)row * (H_ / 2) + (ja >> 1), pk);
          }
          if (t == T_ - 1) {
            hn[(size_t)l * B_ * H_ + (size_t)b * H_ + (j0 + lm)] = v0;
            hn[(size_t)l * B_ * H_ + (size_t)b * H_ + (j0 + 16 + lm)] = v1;
          }
        }
      }
      __syncthreads();  // drains all waves' stores -> release
      if (tid == 0) ast32(myline, (unsigned)(t + 2));
    }
  } else {
    // ===================== GEMM role =====================
    const int gid = bid - 64;
    unsigned short* smem = (unsigned short*)lds;
    unsigned minRec[4] = {0u, 0u, 0u, 0u};
    for (int u = gid; u < NU; u += NGEMM) {
      const int c = u / UPC, v = u % UPC;
      if (v < 64) {
        // layer-0 xin tile
        const int mt = v >> 3, nt = v & 7;
        if (c >= 2) {
          unsigned bp = (unsigned)(16 * c - 15);
          if (minRec[0] < bp) minRec[0] = wait16min(rprog + 0 * 512, bp);
        }
        unsigned* xo = (unsigned*)(xin + (size_t)(0 * 2 + (c & 1)) * (ROWS * H_));
        tile_l0(x, c, Wih0, bih0, bhh0, xo, mt, nt, smem);
        __syncthreads();
        if (tid == 0)
          __hip_atomic_fetch_add(gchunk + (size_t)(0 * NCH + c) * 32, 1u,
                                 __ATOMIC_RELAXED, __HIP_MEMORY_SCOPE_AGENT);
      } else if (v < 160) {
        const int v2 = v - 64;
        const int l = 1 + v2 / 32;
        const int w = v2 & 31, mt = w >> 2, ng = w & 3;
        unsigned tgt = (unsigned)(16 * c + 17);
        if (minRec[l - 1] < tgt) minRec[l - 1] = wait16min(rprog + (size_t)(l - 1) * 512, tgt);
        if (c >= 2) {
          unsigned bp = (unsigned)(16 * c - 15);
          if (minRec[l] < bp) minRec[l] = wait16min(rprog + (size_t)l * 512, bp);
        }
        const unsigned short* A = seqr + (size_t)((l - 1) * 4 + (c & 3)) * (ROWS * H_);
        unsigned* xo = (unsigned*)(xin + (size_t)(l * 2 + (c & 1)) * (ROWS * H_));
        tile_seq(A, WihL + (size_t)(l - 1) * H_ * H_,
                 bihL + (size_t)(l - 1) * H_, bhhL + (size_t)(l - 1) * H_,
                 xo, mt, ng, smem);
        __syncthreads();
        if (tid == 0)
          __hip_atomic_fetch_add(gchunk + (size_t)(l * NCH + c) * 32, 1u,
                                 __ATOMIC_RELAXED, __HIP_MEMORY_SCOPE_AGENT);
      } else {
        const int mt = v - 160;
        unsigned tgt = (unsigned)(16 * c + 17);
        if (minRec[3] < tgt) minRec[3] = wait16min(rprog + (size_t)3 * 512, tgt);
        const unsigned short* A = seqr + (size_t)(3 * 4 + (c & 3)) * (ROWS * H_);
        tile_fc(A, Wfc, bfc, out, c, mt, smem);
        __syncthreads();
        if (tid == 0)
          __hip_atomic_fetch_add(gfc + (size_t)c * 32, 1u,
                                 __ATOMIC_RELAXED, __HIP_MEMORY_SCOPE_AGENT);
      }
    }
  }
}

// ---------------------------------------------------------------------------
// ws layout (bytes):
//   0      rprog  (64 lines x 128 B = 8 KB)
//   8192   gchunk (4*32 lines x 128 B = 16 KB)
//   24576  gfc    (32 lines x 128 B = 4 KB)
//   65536  ring   (4l x 2bg x 2slot x 32768 u16 = 1 MB)
//   +1MB   xin    (4l x 2slot x 1024 x 1024 u16 = 16 MB)
//   +16MB  seqr   (4l x 4slot x 1024 x 1024 u16 = 32 MB)
// total ~49.1 MB.
// ---------------------------------------------------------------------------
extern "C" void kernel_launch(void* const* d_in, const int* in_sizes, int n_in,
                              void* d_out, int out_size, void* d_ws, size_t ws_size,
                              hipStream_t stream) {
  const float* x = (const float*)d_in[0];
  const float* hidden = (const float*)d_in[1];
  const float* Wih0 = (const float*)d_in[2];
  const float* Whh0 = (const float*)d_in[3];
  const float* bih0 = (const float*)d_in[4];
  const float* bhh0 = (const float*)d_in[5];
  const float* WihL = (const float*)d_in[6];
  const float* WhhL = (const float*)d_in[7];
  const float* bihL = (const float*)d_in[8];
  const float* bhhL = (const float*)d_in[9];
  const float* Wfc = (const float*)d_in[10];
  const float* bfc = (const float*)d_in[11];
  float* out = (float*)d_out;
  float* hn = out + (size_t)M_ * O_;

  char* ws = (char*)d_ws;
  unsigned* rprog = (unsigned*)ws;
  unsigned* gchunk = (unsigned*)(ws + 8192);
  unsigned* gfc = (unsigned*)(ws + 24576);
  unsigned short* ring = (unsigned short*)(ws + 65536);
  unsigned short* xin = (unsigned short*)(ws + 65536 + (1u << 20));
  unsigned short* seqr = (unsigned short*)(ws + 65536 + (1u << 20) + (16u << 20));

  hipMemsetAsync(ws, 0, 65536, stream);  // all progress counters

  hipFuncSetAttribute((const void*)fused_k, hipFuncAttributeMaxDynamicSharedMemorySize,
                      64 * 1024);
  fused_k<<<256, 256, 64 * 1024, stream>>>(x, hidden, Wih0, Whh0, bih0, bhh0,
                                           WihL, WhhL, bihL, bhhL, Wfc, bfc,
                                           out, hn, rprog, gchunk, gfc,
                                           ring, xin, seqr);
}

// Round 7
// 3357.841 us; speedup vs baseline: 3.0349x; 3.0349x over previous
//
#include <hip/hip_runtime.h>

// SimpleRNN: B=64,T=512,I=128,H=1024,L=4,O=128
// Round 7: round-6 fused design with DEDICATED GEMM block assignment
// (no cross-layer backward chains through shared work lists):
//   bid 0..63    rec blocks (4 layers x 2 bg x 8 members), unchanged from r6
//   bid 64..127  l0 xin tiles (64 blocks, 1 tile/chunk)
//   bid 128..159 l1 xin tiles (32 blocks)
//   bid 160..191 l2 xin tiles
//   bid 192..223 l3 xin tiles
//   bid 224..231 FC tiles (8 blocks)
//   bid 232..255 exit immediately
// Plus: GEMM A-stage uses single 16B LDS stores (r6's paired 8B stores were
// 8-way bank conflicts).
#define B_ 64
#define T_ 512
#define I_ 128
#define H_ 1024
#define L_ 4
#define O_ 128
#define M_ (B_ * T_)
#define S_ 16               // chunk steps
#define NCH 32              // T_/S_
#define ROWS 1024           // S_*B_ rows per chunk

typedef __attribute__((ext_vector_type(8))) short bf16x8_t;
typedef __attribute__((ext_vector_type(4))) float f32x4_t;
typedef __attribute__((ext_vector_type(4))) unsigned int u32x4_t;

__device__ __forceinline__ unsigned short f2bf(float v) {
  unsigned int u = __builtin_bit_cast(unsigned int, v);
  u += 0x7FFFu + ((u >> 16) & 1u);
  return (unsigned short)(u >> 16);
}
__device__ __forceinline__ float bf2f(unsigned short h) {
  return __builtin_bit_cast(float, ((unsigned int)h) << 16);
}
__device__ __forceinline__ f32x4_t mfma16(bf16x8_t a, bf16x8_t b, f32x4_t c) {
  return __builtin_amdgcn_mfma_f32_16x16x32_bf16(a, b, c, 0, 0, 0);
}
__device__ __forceinline__ unsigned aldc(const unsigned* p) {
  return __hip_atomic_load(p, __ATOMIC_RELAXED, __HIP_MEMORY_SCOPE_AGENT);
}
__device__ __forceinline__ unsigned long long ald64(const unsigned long long* p) {
  return __hip_atomic_load(p, __ATOMIC_RELAXED, __HIP_MEMORY_SCOPE_AGENT);
}
__device__ __forceinline__ void ast32(unsigned* p, unsigned v) {
  __hip_atomic_store(p, v, __ATOMIC_RELAXED, __HIP_MEMORY_SCOPE_AGENT);
}

// Poll 16 counter lines (stride 32 u32) until all >= target; return group min.
__device__ __forceinline__ unsigned wait16min(const unsigned* base, unsigned target) {
  const int i = threadIdx.x & 15;
  unsigned v;
  while (true) {
    v = aldc(base + i * 32);
    if (__ballot(v < target) == 0ull) break;
    __builtin_amdgcn_s_sleep(4);
  }
  unsigned mn = v;
  mn = min(mn, (unsigned)__shfl_xor((int)mn, 1));
  mn = min(mn, (unsigned)__shfl_xor((int)mn, 2));
  mn = min(mn, (unsigned)__shfl_xor((int)mn, 4));
  mn = min(mn, (unsigned)__shfl_xor((int)mn, 8));
  return mn;
}
// Single-counter wait; one wave spins, the rest park on the barrier.
__device__ __forceinline__ void wait_cnt_blk(const unsigned* p, unsigned target) {
  if (threadIdx.x < 64) {
    while (aldc(p) < target) __builtin_amdgcn_s_sleep(8);
  }
  __syncthreads();
}

// ---------------------------------------------------------------------------
// GEMM tiles (r6-proven math; A-stage stores now 16B).
// ---------------------------------------------------------------------------
// xin tile for layers 1..3: 128 rows x 256 cols, K=1024, B hi-only.
__device__ void tile_seq(const unsigned short* __restrict__ A,
                         const float* __restrict__ W,
                         const float* __restrict__ b1, const float* __restrict__ b2,
                         unsigned* __restrict__ xo, int mt, int ng,
                         unsigned short* smem) {
  const int tid = threadIdx.x;
  const int wave = tid >> 6, lane = tid & 63;
  const int wm = wave >> 1, wn = wave & 1;
  const int lm = lane & 15, lk = lane >> 4;
  unsigned short* Ah = smem;          // 8192 u16
  unsigned short* Bh = smem + 8192;   // 16384 u16
  f32x4_t acc[4][8] = {};
  for (int kc = 0; kc < H_; kc += 64) {
    __syncthreads();
#pragma unroll
    for (int p = 0; p < 4; ++p) {
      int fl = p * 256 + tid;
      int row = fl & 127, ks = fl >> 7;
      int kk = kc + (ks >> 2) * 32 + (ks & 3) * 8;
      const unsigned long long* s8 =
          (const unsigned long long*)(A + (size_t)(mt * 128 + row) * H_ + kk);
      union { u32x4_t v; unsigned long long w[2]; } tmp;
      tmp.w[0] = ald64(s8);
      tmp.w[1] = ald64(s8 + 1);
      *(u32x4_t*)(Ah + fl * 8) = tmp.v;
    }
#pragma unroll
    for (int p = 0; p < 8; ++p) {
      int fl = p * 256 + tid;
      int col = fl & 255, ks = fl >> 8;
      int kk = kc + (ks >> 2) * 32 + (ks & 3) * 8;
      const float* src = W + (size_t)(ng * 256 + col) * H_ + kk;
      union { bf16x8_t s; unsigned short u[8]; } th;
#pragma unroll
      for (int e = 0; e < 8; ++e) th.u[e] = (short)f2bf(src[e]);
      *(bf16x8_t*)(Bh + fl * 8) = th.s;
    }
    __syncthreads();
#pragma unroll
    for (int kit = 0; kit < 2; ++kit) {
      bf16x8_t bfr[8];
#pragma unroll
      for (int n = 0; n < 8; ++n)
        bfr[n] = *(const bf16x8_t*)(Bh + ((kit * 4 + lk) * 256 + wn * 128 + n * 16 + lm) * 8);
#pragma unroll
      for (int m = 0; m < 4; ++m) {
        bf16x8_t a = *(const bf16x8_t*)(Ah + ((kit * 4 + lk) * 128 + wm * 64 + m * 16 + lm) * 8);
#pragma unroll
        for (int n = 0; n < 8; ++n) acc[m][n] = mfma16(a, bfr[n], acc[m][n]);
      }
    }
  }
#pragma unroll
  for (int n = 0; n < 8; ++n) {
    int col = ng * 256 + wn * 128 + n * 16 + lm;
    float bv = b1[col] + b2[col];
#pragma unroll
    for (int m = 0; m < 4; ++m) {
#pragma unroll
      for (int r = 0; r < 4; ++r) {
        int row = mt * 128 + wm * 64 + m * 16 + lk * 4 + r;
        unsigned hv = f2bf(acc[m][n][r] + bv);
        unsigned ov = (unsigned)__shfl_xor((int)hv, 1);
        if (!(lm & 1)) ast32(xo + (size_t)row * (H_ / 2) + (col >> 1), hv | (ov << 16));
      }
    }
  }
}

// layer-0 input projection: A = x fp32 (split hi/lo), B = Wih0 hi/lo, K=128.
__device__ void tile_l0(const float* __restrict__ x, int c,
                        const float* __restrict__ W,
                        const float* __restrict__ b1, const float* __restrict__ b2,
                        unsigned* __restrict__ xo, int mt, int nt,
                        unsigned short* smem) {
  const int tid = threadIdx.x;
  const int wave = tid >> 6, lane = tid & 63;
  const int wm = wave >> 1, wn = wave & 1;
  const int lm = lane & 15, lk = lane >> 4;
  unsigned short* Ahi = smem;
  unsigned short* Alo = smem + 8192;
  unsigned short* Bhi = smem + 16384;
  unsigned short* Blo = smem + 24576;
  f32x4_t acc[4][4] = {};
  for (int kc = 0; kc < I_; kc += 64) {
    __syncthreads();
#pragma unroll
    for (int p = 0; p < 4; ++p) {
      int fl = p * 256 + tid;
      int row = fl & 127, ks = fl >> 7;
      int kk = kc + (ks >> 2) * 32 + (ks & 3) * 8;
      int srow = mt * 128 + row;
      int b = srow & 63, tl = srow >> 6;
      const float* src = x + ((size_t)b * T_ + c * S_ + tl) * I_ + kk;
      union { bf16x8_t s; unsigned short u[8]; } th, tl2;
#pragma unroll
      for (int e = 0; e < 8; ++e) {
        float v = src[e];
        unsigned short h = f2bf(v);
        th.u[e] = (short)h;
        tl2.u[e] = (short)f2bf(v - bf2f(h));
      }
      *(bf16x8_t*)(Ahi + fl * 8) = th.s;
      *(bf16x8_t*)(Alo + fl * 8) = tl2.s;
    }
#pragma unroll
    for (int p = 0; p < 4; ++p) {
      int fl = p * 256 + tid;
      int row = fl & 127, ks = fl >> 7;
      int kk = kc + (ks >> 2) * 32 + (ks & 3) * 8;
      const float* src = W + (size_t)(nt * 128 + row) * I_ + kk;
      union { bf16x8_t s; unsigned short u[8]; } th, tl2;
#pragma unroll
      for (int e = 0; e < 8; ++e) {
        float v = src[e];
        unsigned short h = f2bf(v);
        th.u[e] = (short)h;
        tl2.u[e] = (short)f2bf(v - bf2f(h));
      }
      *(bf16x8_t*)(Bhi + fl * 8) = th.s;
      *(bf16x8_t*)(Blo + fl * 8) = tl2.s;
    }
    __syncthreads();
#pragma unroll
    for (int kit = 0; kit < 2; ++kit) {
      bf16x8_t bhf[4], blf[4];
#pragma unroll
      for (int n = 0; n < 4; ++n) {
        int off = ((kit * 4 + lk) * 128 + wn * 64 + n * 16 + lm) * 8;
        bhf[n] = *(const bf16x8_t*)(Bhi + off);
        blf[n] = *(const bf16x8_t*)(Blo + off);
      }
#pragma unroll
      for (int m = 0; m < 4; ++m) {
        int off = ((kit * 4 + lk) * 128 + wm * 64 + m * 16 + lm) * 8;
        bf16x8_t a = *(const bf16x8_t*)(Ahi + off);
        bf16x8_t al = *(const bf16x8_t*)(Alo + off);
#pragma unroll
        for (int n = 0; n < 4; ++n) {
          acc[m][n] = mfma16(a, bhf[n], acc[m][n]);
          acc[m][n] = mfma16(a, blf[n], acc[m][n]);
          acc[m][n] = mfma16(al, bhf[n], acc[m][n]);
        }
      }
    }
  }
#pragma unroll
  for (int n = 0; n < 4; ++n) {
    int col = nt * 128 + wn * 64 + n * 16 + lm;
    float bv = b1[col] + b2[col];
#pragma unroll
    for (int m = 0; m < 4; ++m) {
#pragma unroll
      for (int r = 0; r < 4; ++r) {
        int row = mt * 128 + wm * 64 + m * 16 + lk * 4 + r;
        unsigned hv = f2bf(acc[m][n][r] + bv);
        unsigned ov = (unsigned)__shfl_xor((int)hv, 1);
        if (!(lm & 1)) ast32(xo + (size_t)row * (H_ / 2) + (col >> 1), hv | (ov << 16));
      }
    }
  }
}

// FC tile: A = seqr l3 chunk (u16 sc1), B = Wfc hi/lo, N=128, out fp32.
__device__ void tile_fc(const unsigned short* __restrict__ A,
                        const float* __restrict__ W, const float* __restrict__ bfc,
                        float* __restrict__ out, int c, int mt,
                        unsigned short* smem) {
  const int tid = threadIdx.x;
  const int wave = tid >> 6, lane = tid & 63;
  const int wm = wave >> 1, wn = wave & 1;
  const int lm = lane & 15, lk = lane >> 4;
  unsigned short* Ah = smem;
  unsigned short* Bhi = smem + 8192;
  unsigned short* Blo = smem + 16384;
  f32x4_t acc[4][4] = {};
  for (int kc = 0; kc < H_; kc += 64) {
    __syncthreads();
#pragma unroll
    for (int p = 0; p < 4; ++p) {
      int fl = p * 256 + tid;
      int row = fl & 127, ks = fl >> 7;
      int kk = kc + (ks >> 2) * 32 + (ks & 3) * 8;
      const unsigned long long* s8 =
          (const unsigned long long*)(A + (size_t)(mt * 128 + row) * H_ + kk);
      union { u32x4_t v; unsigned long long w[2]; } tmp;
      tmp.w[0] = ald64(s8);
      tmp.w[1] = ald64(s8 + 1);
      *(u32x4_t*)(Ah + fl * 8) = tmp.v;
    }
#pragma unroll
    for (int p = 0; p < 4; ++p) {
      int fl = p * 256 + tid;
      int col = fl & 127, ks = fl >> 7;
      int kk = kc + (ks >> 2) * 32 + (ks & 3) * 8;
      const float* src = W + (size_t)col * H_ + kk;
      union { bf16x8_t s; unsigned short u[8]; } th, tl2;
#pragma unroll
      for (int e = 0; e < 8; ++e) {
        float v = src[e];
        unsigned short h = f2bf(v);
        th.u[e] = (short)h;
        tl2.u[e] = (short)f2bf(v - bf2f(h));
      }
      *(bf16x8_t*)(Bhi + fl * 8) = th.s;
      *(bf16x8_t*)(Blo + fl * 8) = tl2.s;
    }
    __syncthreads();
#pragma unroll
    for (int kit = 0; kit < 2; ++kit) {
      bf16x8_t bhf[4], blf[4];
#pragma unroll
      for (int n = 0; n < 4; ++n) {
        int off = ((kit * 4 + lk) * 128 + wn * 64 + n * 16 + lm) * 8;
        bhf[n] = *(const bf16x8_t*)(Bhi + off);
        blf[n] = *(const bf16x8_t*)(Blo + off);
      }
#pragma unroll
      for (int m = 0; m < 4; ++m) {
        bf16x8_t a = *(const bf16x8_t*)(Ah + ((kit * 4 + lk) * 128 + wm * 64 + m * 16 + lm) * 8);
#pragma unroll
        for (int n = 0; n < 4; ++n) {
          acc[m][n] = mfma16(a, bhf[n], acc[m][n]);
          acc[m][n] = mfma16(a, blf[n], acc[m][n]);
        }
      }
    }
  }
#pragma unroll
  for (int n = 0; n < 4; ++n) {
    int col = wn * 64 + n * 16 + lm;
    float bv = bfc[col];
#pragma unroll
    for (int m = 0; m < 4; ++m) {
#pragma unroll
      for (int r = 0; r < 4; ++r) {
        int srow = mt * 128 + wm * 64 + m * 16 + lk * 4 + r;
        int b = srow & 63, tl = srow >> 6;
        out[((size_t)b * T_ + c * S_ + tl) * O_ + col] = acc[m][n][r] + bv;
      }
    }
  }
}

// ---------------------------------------------------------------------------
// Fused persistent kernel with dedicated roles.
// ---------------------------------------------------------------------------
__global__ __launch_bounds__(256, 1) void fused_k(
    const float* __restrict__ x, const float* __restrict__ hidden,
    const float* __restrict__ Wih0, const float* __restrict__ Whh0,
    const float* __restrict__ bih0, const float* __restrict__ bhh0,
    const float* __restrict__ WihL, const float* __restrict__ WhhL,
    const float* __restrict__ bihL, const float* __restrict__ bhhL,
    const float* __restrict__ Wfc, const float* __restrict__ bfc,
    float* __restrict__ out, float* __restrict__ hn,
    unsigned* __restrict__ rprog, unsigned* __restrict__ gchunk,
    unsigned* __restrict__ gfc,
    unsigned short* __restrict__ ring, unsigned short* __restrict__ xin,
    unsigned short* __restrict__ seqr) {
  extern __shared__ char lds[];
  const int tid = threadIdx.x;
  const int wave = tid >> 6, lane = tid & 63;
  const int lm = lane & 15, lk = lane >> 4;
  const int bid = blockIdx.x;

  if (bid < 64) {
    // ===================== recurrence role (unchanged from r6) =============
    const int l = bid >> 4, sub = bid & 15, bg = sub >> 3, me = sub & 7;
    const int j0 = me * 128 + wave * 32;

    const float* Whh = (l == 0) ? Whh0 : WhhL + (size_t)(l - 1) * H_ * H_;
    bf16x8_t bh0[32], bh1[32];
#pragma unroll
    for (int kit = 0; kit < 32; ++kit) {
      const float* s0 = Whh + (size_t)(j0 + lm) * H_ + kit * 32 + lk * 8;
      const float* s1 = Whh + (size_t)(j0 + 16 + lm) * H_ + kit * 32 + lk * 8;
      union { bf16x8_t s; unsigned short u[8]; } t0, t1;
#pragma unroll
      for (int e = 0; e < 8; ++e) {
        t0.u[e] = (short)f2bf(s0[e]);
        t1.u[e] = (short)f2bf(s1[e]);
      }
      bh0[kit] = t0.s;
      bh1[kit] = t1.s;
    }

    // init h0 -> ring slot 1
    {
      unsigned* r1 = (unsigned*)(ring + ((size_t)(l * 2 + bg) * 2 + 1) * 32768);
#pragma unroll
      for (int q = 0; q < 8; ++q) {
        int g32 = me * 2048 + q * 256 + tid;
        int joct = g32 >> 7, rem = g32 & 127;
        int b32 = rem >> 2, jp = rem & 3;
        int je = joct * 8 + jp * 2;
        const float* hp = hidden + (size_t)l * B_ * H_ + (bg * 32 + b32) * H_ + je;
        ast32(r1 + g32, (unsigned)f2bf(hp[0]) | ((unsigned)f2bf(hp[1]) << 16));
      }
    }
    __syncthreads();  // drains vmcnt -> release
    unsigned* myline = rprog + ((size_t)((l * 2 + bg) * 8 + me)) * 32;
    if (tid == 0) ast32(myline, 1u);
    const unsigned* ownB = rprog + (size_t)(l * 2 + bg) * 8 * 32;

    for (int t = 0; t < T_; ++t) {
      const int c = t >> 4;
      if ((t & 15) == 0) {
        wait_cnt_blk(gchunk + (size_t)(l * NCH + c) * 32, l == 0 ? 64u : 32u);
        if (c >= 4) {
          if (l < 3) wait_cnt_blk(gchunk + (size_t)((l + 1) * NCH + (c - 4)) * 32, 32u);
          else       wait_cnt_blk(gfc + (size_t)(c - 4) * 32, 8u);
        }
      }
      // xin loads (independent of h barrier)
      const unsigned* xb = (const unsigned*)xin + (size_t)(l * 2 + (c & 1)) * (ROWS * H_ / 2);
      unsigned xv[2][2][4];
#pragma unroll
      for (int nt = 0; nt < 2; ++nt)
#pragma unroll
        for (int bt = 0; bt < 2; ++bt)
#pragma unroll
          for (int r = 0; r < 4; ++r) {
            int b = bg * 32 + bt * 16 + lk * 4 + r;
            int row = (t & 15) * 64 + b;
            int j = j0 + nt * 16 + lm;
            xv[nt][bt][r] = aldc(xb + (size_t)row * (H_ / 2) + (j >> 1));
          }
      // own-group barrier: all 8 members finished step t-1
      {
        const int i = tid & 7;
        while (true) {
          unsigned v = aldc(ownB + i * 32);
          if (__ballot(v < (unsigned)(t + 1)) == 0ull) break;
          __builtin_amdgcn_s_sleep(1);
        }
      }
      // h slice (64 KB) -> LDS
      {
        const unsigned long long* hp64 = (const unsigned long long*)(
            ring + ((size_t)(l * 2 + bg) * 2 + ((t & 1) ^ 1)) * 32768);
        unsigned long long ht[32];
#pragma unroll
        for (int i = 0; i < 32; ++i) ht[i] = ald64(hp64 + i * 256 + tid);
#pragma unroll
        for (int i = 0; i < 32; ++i)
          ((unsigned long long*)lds)[i * 256 + tid] = ht[i];
      }
      __syncthreads();
      f32x4_t acc00 = {0.f, 0.f, 0.f, 0.f}, acc01 = acc00, acc10 = acc00, acc11 = acc00;
#pragma unroll
      for (int kit = 0; kit < 32; ++kit) {
        const char* fo = lds + (size_t)((kit * 4 + lk) * 32) * 16;
        bf16x8_t a0 = *(const bf16x8_t*)(fo + (size_t)lm * 16);
        bf16x8_t a1 = *(const bf16x8_t*)(fo + (size_t)(16 + lm) * 16);
        acc00 = mfma16(a0, bh0[kit], acc00);
        acc01 = mfma16(a1, bh0[kit], acc01);
        acc10 = mfma16(a0, bh1[kit], acc10);
        acc11 = mfma16(a1, bh1[kit], acc11);
      }
      // epilogue
      unsigned* rw = (unsigned*)(ring + ((size_t)(l * 2 + bg) * 2 + (t & 1)) * 32768);
      unsigned* sw = (unsigned*)(seqr + (size_t)(l * 4 + (c & 3)) * (ROWS * H_));
      const bool evenl = !(lm & 1);
#pragma unroll
      for (int bt = 0; bt < 2; ++bt) {
#pragma unroll
        for (int r = 0; r < 4; ++r) {
          const int b32 = bt * 16 + lk * 4 + r;
          const int b = bg * 32 + b32;
          const int row = (t & 15) * 64 + b;
          const f32x4_t* p0 = bt ? &acc01 : &acc00;
          const f32x4_t* p1 = bt ? &acc11 : &acc10;
          float v0 = (*p0)[r] + bf2f((unsigned short)(xv[0][bt][r] >> ((lm & 1) * 16)));
          float v1 = (*p1)[r] + bf2f((unsigned short)(xv[1][bt][r] >> ((lm & 1) * 16)));
          v0 = fmaxf(v0, 0.f);
          v1 = fmaxf(v1, 0.f);
          unsigned h0v = f2bf(v0), h1v = f2bf(v1);
          unsigned o0 = (unsigned)__shfl_xor((int)h0v, 1);
          unsigned o1 = (unsigned)__shfl_xor((int)h1v, 1);
          if (evenl) {
            int j = j0 + lm;
            unsigned pk = h0v | (o0 << 16);
            ast32(rw + ((j >> 3) * 32 + b32) * 4 + ((j & 7) >> 1), pk);
            ast32(sw + (size_t)row * (H_ / 2) + (j >> 1), pk);
          } else {
            int j = j0 + 16 + lm;
            int ja = j & ~1;
            unsigned pk = o1 | (h1v << 16);
            ast32(rw + ((ja >> 3) * 32 + b32) * 4 + ((ja & 7) >> 1), pk);
            ast32(sw + (size_t)row * (H_ / 2) + (ja >> 1), pk);
          }
          if (t == T_ - 1) {
            hn[(size_t)l * B_ * H_ + (size_t)b * H_ + (j0 + lm)] = v0;
            hn[(size_t)l * B_ * H_ + (size_t)b * H_ + (j0 + 16 + lm)] = v1;
          }
        }
      }
      __syncthreads();  // drains all waves' stores -> release
      if (tid == 0) ast32(myline, (unsigned)(t + 2));
    }
  } else if (bid < 128) {
    // ===================== l0 xin role: 64 blocks, 1 tile/chunk ============
    const int g2 = bid - 64;
    const int mt = g2 >> 3, nt = g2 & 7;
    unsigned short* smem = (unsigned short*)lds;
    unsigned minRec = 0u;
    for (int c = 0; c < NCH; ++c) {
      if (c >= 2) {  // WAR: rec[0] consumed chunk c-2 from xin slot (c&1)
        unsigned bp = (unsigned)(16 * c - 15);
        if (minRec < bp) minRec = wait16min(rprog, bp);
      }
      unsigned* xo = (unsigned*)(xin + (size_t)(c & 1) * (ROWS * H_));
      tile_l0(x, c, Wih0, bih0, bhh0, xo, mt, nt, smem);
      __syncthreads();
      if (tid == 0)
        __hip_atomic_fetch_add(gchunk + (size_t)c * 32, 1u,
                               __ATOMIC_RELAXED, __HIP_MEMORY_SCOPE_AGENT);
    }
  } else if (bid < 224) {
    // ===================== l1..3 xin role: 32 blocks per layer =============
    const int l = 1 + ((bid - 128) >> 5);
    const int w = (bid - 128) & 31;
    const int mt = w >> 2, ng = w & 3;
    unsigned short* smem = (unsigned short*)lds;
    unsigned minUp = 0u, minOwn = 0u;
    const float* Wih = WihL + (size_t)(l - 1) * H_ * H_;
    const float* b1 = bihL + (size_t)(l - 1) * H_;
    const float* b2 = bhhL + (size_t)(l - 1) * H_;
    for (int c = 0; c < NCH; ++c) {
      unsigned tgt = (unsigned)(16 * c + 17);  // RAW: rec[l-1] finished chunk c
      if (minUp < tgt) minUp = wait16min(rprog + (size_t)(l - 1) * 512, tgt);
      if (c >= 2) {  // WAR: rec[l] consumed chunk c-2 from xin slot (c&1)
        unsigned bp = (unsigned)(16 * c - 15);
        if (minOwn < bp) minOwn = wait16min(rprog + (size_t)l * 512, bp);
      }
      const unsigned short* A = seqr + (size_t)((l - 1) * 4 + (c & 3)) * (ROWS * H_);
      unsigned* xo = (unsigned*)(xin + (size_t)(l * 2 + (c & 1)) * (ROWS * H_));
      tile_seq(A, Wih, b1, b2, xo, mt, ng, smem);
      __syncthreads();
      if (tid == 0)
        __hip_atomic_fetch_add(gchunk + (size_t)(l * NCH + c) * 32, 1u,
                               __ATOMIC_RELAXED, __HIP_MEMORY_SCOPE_AGENT);
    }
  } else if (bid < 232) {
    // ===================== FC role: 8 blocks ===============================
    const int mt = bid - 224;
    unsigned short* smem = (unsigned short*)lds;
    unsigned minRec3 = 0u;
    for (int c = 0; c < NCH; ++c) {
      unsigned tgt = (unsigned)(16 * c + 17);
      if (minRec3 < tgt) minRec3 = wait16min(rprog + (size_t)3 * 512, tgt);
      const unsigned short* A = seqr + (size_t)(3 * 4 + (c & 3)) * (ROWS * H_);
      tile_fc(A, Wfc, bfc, out, c, mt, smem);
      __syncthreads();
      if (tid == 0)
        __hip_atomic_fetch_add(gfc + (size_t)c * 32, 1u,
                               __ATOMIC_RELAXED, __HIP_MEMORY_SCOPE_AGENT);
    }
  }
  // bid >= 232: exit immediately.
}

// ---------------------------------------------------------------------------
// ws layout (bytes):
//   0      rprog  (64 lines x 128 B = 8 KB)
//   8192   gchunk (4*32 lines x 128 B = 16 KB)
//   24576  gfc    (32 lines x 128 B = 4 KB)
//   65536  ring   (4l x 2bg x 2slot x 32768 u16 = 1 MB)
//   +1MB   xin    (4l x 2slot x 1024 x 1024 u16 = 16 MB)
//   +16MB  seqr   (4l x 4slot x 1024 x 1024 u16 = 32 MB)
// total ~49.1 MB.
// ---------------------------------------------------------------------------
extern "C" void kernel_launch(void* const* d_in, const int* in_sizes, int n_in,
                              void* d_out, int out_size, void* d_ws, size_t ws_size,
                              hipStream_t stream) {
  const float* x = (const float*)d_in[0];
  const float* hidden = (const float*)d_in[1];
  const float* Wih0 = (const float*)d_in[2];
  const float* Whh0 = (const float*)d_in[3];
  const float* bih0 = (const float*)d_in[4];
  const float* bhh0 = (const float*)d_in[5];
  const float* WihL = (const float*)d_in[6];
  const float* WhhL = (const float*)d_in[7];
  const float* bihL = (const float*)d_in[8];
  const float* bhhL = (const float*)d_in[9];
  const float* Wfc = (const float*)d_in[10];
  const float* bfc = (const float*)d_in[11];
  float* out = (float*)d_out;
  float* hn = out + (size_t)M_ * O_;

  char* ws = (char*)d_ws;
  unsigned* rprog = (unsigned*)ws;
  unsigned* gchunk = (unsigned*)(ws + 8192);
  unsigned* gfc = (unsigned*)(ws + 24576);
  unsigned short* ring = (unsigned short*)(ws + 65536);
  unsigned short* xin = (unsigned short*)(ws + 65536 + (1u << 20));
  unsigned short* seqr = (unsigned short*)(ws + 65536 + (1u << 20) + (16u << 20));

  hipMemsetAsync(ws, 0, 65536, stream);  // all progress counters

  hipFuncSetAttribute((const void*)fused_k, hipFuncAttributeMaxDynamicSharedMemorySize,
                      64 * 1024);
  fused_k<<<256, 256, 64 * 1024, stream>>>(x, hidden, Wih0, Whh0, bih0, bhh0,
                                           WihL, WhhL, bihL, bhhL, Wfc, bfc,
                                           out, hn, rprog, gchunk, gfc,
                                           ring, xin, seqr);
}